// Round 3
// baseline (1345.123 us; speedup 1.0000x reference)
//
#include <hip/hip_runtime.h>
#include <cstdint>
#include <cstddef>

// Problem shape (fixed): B=4, Sq=2048 -> S=8192 tokens, M=1024, E=8, H=4096,
// C=S/E=1024 capacity.
// WS BUDGET: keep total workspace <= ~84 MB.
// R6: DIAGNOSTIC ROUND. gemm1_kernel repeats its idempotent body 4x so it
// rises above the harness's ~77us workspace-poison fills and shows up in the
// rocprof top-5 WITH counters (dur/4 = true time, MfmaUtil, BANK_CONFLICT,
// VGPR). REMOVE THE x4 NEXT ROUND. Also real changes: full-tile 2-buffer
// staging (stage whole tile t+1 at top of tile t; boundary vmcnt(0) drains
// loads issued ~4 phases earlier -> near-free), 128B rows + 3-bit XOR
// both-sides swizzle; memsets folded into gate_kernel (-2 dispatches).
#define S_TOK 8192
#define MDIM  1024
#define EEXP  8
#define HDIM  4096
#define HHALF 2048
#define CAP   1024

typedef __attribute__((ext_vector_type(8))) short short8v;   // 8 bf16 in 4 VGPRs
typedef __attribute__((ext_vector_type(4))) float f32x4;

__device__ __forceinline__ short f2bf(float f) {
    __bf16 b = (__bf16)f;                 // RNE hardware convert on gfx950
    return __builtin_bit_cast(short, b);
}

__device__ __forceinline__ void gld_lds16(const void* g, void* l) {
    __builtin_amdgcn_global_load_lds(
        (const __attribute__((address_space(1))) void*)g,
        (__attribute__((address_space(3))) void*)l, 16, 0, 0);
}

#define BAR() asm volatile("s_barrier" ::: "memory")
#define WAIT_VM(N) asm volatile("s_waitcnt vmcnt(" #N ")" ::: "memory")

// ---------------------------------------------------------------------------
// K1: gating. One wave per token, fp64 accumulation -> exactly-rounded logits
// so argmax matches the numpy reference. graw = 1/sum(exp(l-m)).
// R6: also zeroes the token's output row and clears slot_token (folds the two
// hipMemsetAsync dispatches into this kernel).
// ---------------------------------------------------------------------------
__global__ void gate_kernel(const float* __restrict__ x, const float* __restrict__ wg,
                            int* __restrict__ eidx, float* __restrict__ graw,
                            float* __restrict__ out, int* __restrict__ slot_token) {
    const int wave = threadIdx.x >> 6, lane = threadIdx.x & 63;
    const int tok = blockIdx.x * 4 + wave;

    // fold of memset(out, 0) + memset(slot_token, -1)
    float* orow = out + (size_t)tok * MDIM;
    const float4 z = {0.f, 0.f, 0.f, 0.f};
#pragma unroll
    for (int i2 = 0; i2 < 4; ++i2)
        *(float4*)(orow + i2 * 256 + lane * 4) = z;
    if (lane == 0) slot_token[tok] = -1;   // slot index space == token space size

    const float* xr = x + (size_t)tok * MDIM;
    double acc[8] = {0, 0, 0, 0, 0, 0, 0, 0};
#pragma unroll
    for (int kk = 0; kk < 16; ++kk) {
        int i = kk * 64 + lane;
        float xv = xr[i];
        float4 w0 = *(const float4*)(wg + (size_t)i * 8);
        float4 w1v = *(const float4*)(wg + (size_t)i * 8 + 4);
        acc[0] += (double)xv * (double)w0.x;
        acc[1] += (double)xv * (double)w0.y;
        acc[2] += (double)xv * (double)w0.z;
        acc[3] += (double)xv * (double)w0.w;
        acc[4] += (double)xv * (double)w1v.x;
        acc[5] += (double)xv * (double)w1v.y;
        acc[6] += (double)xv * (double)w1v.z;
        acc[7] += (double)xv * (double)w1v.w;
    }
#pragma unroll
    for (int off = 32; off >= 1; off >>= 1) {
#pragma unroll
        for (int e = 0; e < 8; ++e) acc[e] += __shfl_down(acc[e], off);
    }
    if (lane == 0) {
        float l[8];
#pragma unroll
        for (int e = 0; e < 8; ++e) l[e] = (float)acc[e];
        float m = l[0]; int best = 0;
#pragma unroll
        for (int e = 1; e < 8; ++e) { if (l[e] > m) { m = l[e]; best = e; } }
        float den = 0.f;
#pragma unroll
        for (int e = 0; e < 8; ++e) den += expf(l[e] - m);
        eidx[tok] = best;
        graw[tok] = 1.0f / den;
    }
}

// ---------------------------------------------------------------------------
// K2: capacity scan. One block; pos[t] = count of earlier same-expert tokens.
// ---------------------------------------------------------------------------
__global__ void scan_kernel(const int* __restrict__ eidx, const float* __restrict__ graw,
                            float* __restrict__ gfin, int* __restrict__ slot_token) {
    __shared__ int cnt[256][8];
    __shared__ int pfx[256][8];
    const int t = threadIdx.x;
    const int base = t * 32;
    int local[8] = {0, 0, 0, 0, 0, 0, 0, 0};
    for (int j = 0; j < 32; ++j) {
        int ev = eidx[base + j];
#pragma unroll
        for (int e = 0; e < 8; ++e) local[e] += (ev == e);
    }
#pragma unroll
    for (int e = 0; e < 8; ++e) cnt[t][e] = local[e];
    __syncthreads();
    if (t < 8) {
        int run = 0;
        for (int i = 0; i < 256; ++i) { pfx[i][t] = run; run += cnt[i][t]; }
    }
    __syncthreads();
    int run[8];
#pragma unroll
    for (int e = 0; e < 8; ++e) run[e] = pfx[t][e];
    for (int j = 0; j < 32; ++j) {
        int tok = base + j;
        int ev = eidx[tok];
        int pos = 0;
#pragma unroll
        for (int e = 0; e < 8; ++e) { if (ev == e) pos = run[e]; run[e] += (ev == e); }
        if (pos < CAP) {
            gfin[tok] = graw[tok];
            slot_token[ev * CAP + pos] = tok;
        } else {
            gfin[tok] = 0.f;
        }
    }
}

// ---------------------------------------------------------------------------
// K3: dispatch — gather kept token rows into bf16 dispA[E*CAP][MDIM].
// ---------------------------------------------------------------------------
__global__ void dispatch_kernel(const float* __restrict__ x, const int* __restrict__ slot_token,
                                short* __restrict__ dispA) {
    const int slot = blockIdx.x;
    const int tok = slot_token[slot];
    const int t = threadIdx.x;
    short4 ov;
    if (tok >= 0) {
        float4 v = *(const float4*)(x + (size_t)tok * MDIM + t * 4);
        ov.x = f2bf(v.x); ov.y = f2bf(v.y); ov.z = f2bf(v.z); ov.w = f2bf(v.w);
    } else {
        ov.x = 0; ov.y = 0; ov.z = 0; ov.w = 0;
    }
    *(short4*)(dispA + (size_t)slot * MDIM + t * 4) = ov;
}

// ---------------------------------------------------------------------------
// K4: fp32 -> bf16 cast + transpose of an [R][C] slab into [C][R] bf16.
// ---------------------------------------------------------------------------
__global__ void cast_transpose_kernel(const float* __restrict__ in, short* __restrict__ out,
                                      int R, int C, int rstride,
                                      size_t in_estride, size_t out_estride) {
    __shared__ float tile[64][65];
    const int e = blockIdx.z;
    const float* src = in + (size_t)e * in_estride;
    short* dst = out + (size_t)e * out_estride;
    const int r0 = blockIdx.x * 64, c0 = blockIdx.y * 64;
    const int t = threadIdx.x;
    const int rr = t >> 4, cq = (t & 15) * 4;
#pragma unroll
    for (int j = 0; j < 4; ++j) {
        int r = rr + j * 16;
        float4 v = *(const float4*)(src + (size_t)(r0 + r) * rstride + c0 + cq);
        tile[r][cq + 0] = v.x; tile[r][cq + 1] = v.y;
        tile[r][cq + 2] = v.z; tile[r][cq + 3] = v.w;
    }
    __syncthreads();
    const int oc = t >> 2, ch = (t & 3) * 16;
    union { short s[16]; int4 v2[2]; } u;
#pragma unroll
    for (int j = 0; j < 16; ++j) u.s[j] = f2bf(tile[ch + j][oc]);
    int4* dp = (int4*)(dst + (size_t)(c0 + oc) * R + r0 + ch);
    dp[0] = u.v2[0]; dp[1] = u.v2[1];
}

// ---------------------------------------------------------------------------
// GEMM core R6: full-tile 2-buffer staging, 128B rows, 3-bit XOR swizzle.
//
// LDS: A [2 buf][256][64] bf16 (64 KB), B [2 buf][BN][64] (64/32 KB).
// Rows are 128B = 8 chunks of 16B; read-side chunk index XOR'd with (row&7);
// staging pre-applies the same XOR to the GLOBAL source chunk so
// global_load_lds dest stays linear (rule 21 both-sides involution).
//
// Schedule per tile t: at tile TOP issue ALL of tile t+1's staging (A 4 + B
// 4/2 gld_lds per thread) into buffer (t+1)&1 — its last readers finished at
// this tile's entry barrier. Phases (ks,prow) read buffer t&1 only. Boundary:
// vmcnt(0) after the last phase's MFMA — the staging loads have had ~4 phases
// (~600 cy) of flight, so the drain is near-free; then one barrier.
//
// Fragment maps (HW-verified m89/m91):
//   A: A[m=lane&15][k=(lane>>4)*8+j];  B: Bt[n=lane&15][k=(lane>>4)*8+j]
//   C/D: col=lane&15, row=(lane>>4)*4+reg
// ---------------------------------------------------------------------------
template <int ROWS>
__device__ __forceinline__ void stage_tile(const short* __restrict__ g, int K, int k0,
                                           short* lds) {
    // ROWS x 64 bf16, 128B rows. Each gld_lds16 instr covers 8 rows (64 lanes
    // x 16B = 1KB, HW dest = base + lane*16). Lane l -> row base+(l>>3),
    // chunk (l&7); source chunk pre-swizzled by ^(row&7) = ^(l>>3).
    const int t = threadIdx.x, w = t >> 6, l = t & 63;
    const int r8 = l >> 3;
    const int swz = ((l & 7) ^ r8) * 8;
#pragma unroll
    for (int j = 0; j < ROWS / 64; ++j) {
        const int rowbase = j * 64 + w * 8;
        gld_lds16(g + (size_t)(rowbase + r8) * K + k0 + swz, lds + rowbase * 64);
    }
}

__device__ __forceinline__ short8v rdfrag64(const short* tile, int row, int kq) {
    // kq = ks*4 + fq : logical 16B-chunk within the 128B row
    return *(const short8v*)(tile + row * 64 + ((kq ^ (row & 7)) * 8));
}

template <int BN, int K>
__device__ __forceinline__ void gemm_core(const short* __restrict__ A,
                                          const short* __restrict__ B,
                                          int m0, int n0,
                                          short* __restrict__ ldsA,
                                          short* __restrict__ ldsB,
                                          f32x4 (&acc)[BN / 32][4]) {
    constexpr int NT    = K / 64;
    constexpr int NWC   = BN / 64;       // col-waves: 4 (BN=256) or 2 (BN=128)
    constexpr int WM    = 32 * NWC;      // per-wave rows: 128 or 64
    constexpr int NPROW = WM / 64;       // prow phases per ks: 2 or 1
    const int tid = threadIdx.x;
    const int wid = tid >> 6, lane = tid & 63;
    const int wr = wid / NWC, wcn = wid % NWC;
    const int fr = lane & 15, fq = lane >> 4;
    const int rowA0 = wr * WM;
    const int rowB0 = wcn * 64;

    const short* Ab = A + (size_t)m0 * K;
    const short* Bb = B + (size_t)n0 * K;

    // prologue: tile 0 into buffer 0
    stage_tile<256>(Ab, K, 0, ldsA);
    stage_tile<BN >(Bb, K, 0, ldsB);
    WAIT_VM(0);
    BAR();

    for (int t = 0; t < NT; ++t) {
        const int buf = t & 1;
        const short* bA = ldsA + buf * (256 * 64);
        const short* bB = ldsB + buf * (BN * 64);
        const bool pf = (t + 1 < NT);
        if (pf) {   // stage ALL of tile t+1 into the other buffer
            stage_tile<256>(Ab, K, (t + 1) * 64, ldsA + (buf ^ 1) * (256 * 64));
            stage_tile<BN >(Bb, K, (t + 1) * 64, ldsB + (buf ^ 1) * (BN * 64));
        }
#pragma unroll
        for (int ks = 0; ks < 2; ++ks) {
            short8v bv[4];
#pragma unroll
            for (int j = 0; j < 4; ++j)
                bv[j] = rdfrag64(bB, rowB0 + j * 16 + fr, ks * 4 + fq);
#pragma unroll
            for (int prow = 0; prow < NPROW; ++prow) {
                short8v av[4];
#pragma unroll
                for (int i = 0; i < 4; ++i)
                    av[i] = rdfrag64(bA, rowA0 + prow * 64 + i * 16 + fr, ks * 4 + fq);
                BAR();
                __builtin_amdgcn_s_setprio(1);
#pragma unroll
                for (int i = 0; i < 4; ++i)
#pragma unroll
                    for (int j = 0; j < 4; ++j)
                        acc[prow * 4 + i][j] = __builtin_amdgcn_mfma_f32_16x16x32_bf16(
                            av[i], bv[j], acc[prow * 4 + i][j], 0, 0, 0);
                __builtin_amdgcn_s_setprio(0);
                if (ks == 1 && prow == NPROW - 1 && pf) { WAIT_VM(0); }  // ~4 phases of slack
                BAR();
            }
        }
    }
}

// Bijective expert->XCD remap: grid is (4,8,8)=256 blocks; blocks with
// lin%8==k (one XCD) become one expert's 32 tiles -> that expert's weight
// panel lives in that XCD's private L2.
__device__ __forceinline__ int3 remap_block() {
    int lin = blockIdx.x + (blockIdx.y << 2) + (blockIdx.z << 5);
    lin = (lin & 7) * 32 + (lin >> 3);
    int3 r;
    r.z = lin >> 5;          // expert
    r.x = lin & 3;           // m-tile
    r.y = (lin >> 2) & 7;    // n-tile
    return r;
}

// GEMM1 half: h[e,c,n] = relu(dispA[e,c,:].w1t[e,n,:] + b1[e,hoff+n])
// *** R6 DIAGNOSTIC: body repeated 4x (idempotent: acc re-zeroed, pure
// stores of identical values). dur_us of this dispatch / 4 = true time.
// REMOVE THE REP LOOP NEXT ROUND. ***
__global__ __launch_bounds__(512, 2)
void gemm1_kernel(const short* __restrict__ dispA, const short* __restrict__ w1t,
                  const float* __restrict__ b1, short* __restrict__ h, int hoff) {
    __shared__ alignas(16) short ldsA[2 * 256 * 64];
    __shared__ alignas(16) short ldsB[2 * 256 * 64];
    const int3 bid = remap_block();
    const int e = bid.z;
    const int m0 = bid.x * 256, n0 = bid.y * 256;

#pragma unroll 1
    for (int rep = 0; rep < 4; ++rep) {
        f32x4 acc[8][4];
#pragma unroll
        for (int i = 0; i < 8; ++i)
#pragma unroll
            for (int j = 0; j < 4; ++j) acc[i][j] = (f32x4){0.f, 0.f, 0.f, 0.f};

        gemm_core<256, MDIM>(dispA + (size_t)e * CAP * MDIM,
                             w1t + (size_t)e * HHALF * MDIM, m0, n0, ldsA, ldsB, acc);

        const int wid = threadIdx.x >> 6, lane = threadIdx.x & 63;
        const int wr = wid >> 2, wcn = wid & 3, fr = lane & 15, fq = lane >> 4;
        const float* b1e = b1 + (size_t)e * HDIM + hoff;
        short* hExp = h + (size_t)e * CAP * HHALF;
#pragma unroll
        for (int nf = 0; nf < 4; ++nf) {
            const int gcol = n0 + wcn * 64 + nf * 16 + fr;
            const float bias = b1e[gcol];
#pragma unroll
            for (int mf = 0; mf < 8; ++mf)
#pragma unroll
                for (int r2 = 0; r2 < 4; ++r2) {
                    const int grow = m0 + wr * 128 + mf * 16 + fq * 4 + r2;
                    float v = acc[mf][nf][r2] + bias;
                    hExp[(size_t)grow * HHALF + gcol] = f2bf(v > 0.f ? v : 0.f);
                }
        }
        __syncthreads();   // isolate reps (drains all counters; 4x only)
    }
}

// GEMM2 half: eo_part[e,c,m] = h[e,c,:].w2t[e,m,:]; scatter (acc[+b2])*gv.
__global__ __launch_bounds__(512, 2)
void gemm2_kernel(const short* __restrict__ h, const short* __restrict__ w2t,
                  const float* __restrict__ b2, const int* __restrict__ slot_token,
                  const float* __restrict__ gfin, float* __restrict__ out,
                  int acc_flag) {
    __shared__ alignas(16) short ldsA[2 * 256 * 64];
    __shared__ alignas(16) short ldsB[2 * 128 * 64];
    const int3 bid = remap_block();
    const int e = bid.z;
    const int m0 = bid.x * 256, n0 = bid.y * 128;

    f32x4 acc[4][4];
#pragma unroll
    for (int i = 0; i < 4; ++i)
#pragma unroll
        for (int j = 0; j < 4; ++j) acc[i][j] = (f32x4){0.f, 0.f, 0.f, 0.f};

    gemm_core<128, HHALF>(h + (size_t)e * CAP * HHALF,
                          w2t + (size_t)e * MDIM * HHALF, m0, n0, ldsA, ldsB, acc);

    const int wid = threadIdx.x >> 6, lane = threadIdx.x & 63;
    const int wr = wid >> 1, wcn = wid & 1, fr = lane & 15, fq = lane >> 4;
    const float* b2e = b2 + (size_t)e * MDIM;
#pragma unroll
    for (int mf = 0; mf < 4; ++mf)
#pragma unroll
        for (int r2 = 0; r2 < 4; ++r2) {
            const int grow = m0 + wr * 64 + mf * 16 + fq * 4 + r2;
            const int tok = slot_token[e * CAP + grow];
            if (tok < 0) continue;
            const float gv = gfin[tok];
            float* orow = out + (size_t)tok * MDIM;
            if (acc_flag == 0) {
#pragma unroll
                for (int nf = 0; nf < 4; ++nf) {
                    const int gcol = n0 + wcn * 64 + nf * 16 + fr;
                    orow[gcol] = (acc[mf][nf][r2] + b2e[gcol]) * gv;
                }
            } else {
#pragma unroll
                for (int nf = 0; nf < 4; ++nf) {
                    const int gcol = n0 + wcn * 64 + nf * 16 + fr;
                    orow[gcol] += acc[mf][nf][r2] * gv;
                }
            }
        }
}

// ---------------------------------------------------------------------------
// Workspace layout (bytes) — TOTAL 84,017,152 B (~80.1 MiB):
//   wt    bf16 [E][2048][1024] ping-pong :        0 .. 33,554,432
//   hbuf  bf16 [E][C][HHALF]             : 33,554,432 .. 67,108,864
//   dispA bf16 [E*C][M]                  : 67,108,864 .. 83,886,080
//   eidx/graw/gfin/slot_token            : 83,886,080 .. 84,017,152
// ---------------------------------------------------------------------------
extern "C" void kernel_launch(void* const* d_in, const int* in_sizes, int n_in,
                              void* d_out, int out_size, void* d_ws, size_t ws_size,
                              hipStream_t stream) {
    const float* x  = (const float*)d_in[0];
    const float* wg = (const float*)d_in[1];
    const float* w1 = (const float*)d_in[2];
    const float* b1 = (const float*)d_in[3];
    const float* w2 = (const float*)d_in[4];
    const float* b2 = (const float*)d_in[5];
    float* out = (float*)d_out;

    char* ws = (char*)d_ws;
    short* wt    = (short*)(ws);
    short* hbuf  = (short*)(ws + 33554432);
    short* dispA = (short*)(ws + 67108864);
    int*   eidx  = (int*)  (ws + 83886080);
    float* graw  = (float*)(ws + 83886080 + 32768);
    float* gfin  = (float*)(ws + 83886080 + 65536);
    int*   slot_token = (int*)(ws + 83886080 + 98304);

    // memsets folded into gate_kernel (out-row zero + slot_token clear)
    gate_kernel<<<S_TOK / 4, 256, 0, stream>>>(x, wg, eidx, graw, out, slot_token);
    scan_kernel<<<1, 256, 0, stream>>>(eidx, graw, gfin, slot_token);
    dispatch_kernel<<<EEXP * CAP, 256, 0, stream>>>(x, slot_token, dispA);

    for (int half = 0; half < 2; ++half) {
        // w1 slab: in [E][M][H], rows r=M (stride H), cols c = hoff..hoff+2048
        cast_transpose_kernel<<<dim3(MDIM / 64, HHALF / 64, EEXP), 256, 0, stream>>>(
            w1 + (size_t)half * HHALF, wt, MDIM, HHALF, HDIM,
            (size_t)MDIM * HDIM, (size_t)HHALF * MDIM);
        gemm1_kernel<<<dim3(4, 8, 8), 512, 0, stream>>>(
            dispA, wt, b1, hbuf, half * HHALF);
        // w2 slab: in [E][H][M], rows r = hoff..hoff+2048 (stride M), cols c=M
        cast_transpose_kernel<<<dim3(HHALF / 64, MDIM / 64, EEXP), 256, 0, stream>>>(
            w2 + (size_t)half * HHALF * MDIM, wt, HHALF, MDIM, MDIM,
            (size_t)HDIM * MDIM, (size_t)MDIM * HHALF);
        gemm2_kernel<<<dim3(4, 8, 8), 512, 0, stream>>>(
            hbuf, wt, b2, slot_token, gfin, out, half);
    }
}

// Round 4
// 621.144 us; speedup vs baseline: 2.1656x; 2.1656x over previous
//
#include <hip/hip_runtime.h>
#include <cstdint>
#include <cstddef>

// Problem shape (fixed): B=4, Sq=2048 -> S=8192 tokens, M=1024, E=8, H=4096,
// C=S/E=1024 capacity.
// WS BUDGET: keep total workspace <= ~84 MB.
// R7: R6 diagnostic showed gemm1 = 116us/rep, MfmaUtil 12%, Occupancy 18%
// (1 block/CU), hbm 1.5 TB/s -> latency-serialized by the per-tile vmcnt(0)
// drain with no co-resident block to overlap (m218: drain0 kills the
// pipeline). Fix: 3-slot BK=32 ring, prefetch distance 2, counted vmcnt(4)/
// vmcnt(3) (never 0 in-loop), ONE barrier per K-step. 64B LDS rows make
// ds_read_b128 bank-uniform (8 dwords/bank = floor) -> no swizzle. LDS 96/72
// KB. x4 rep loop removed.
#define S_TOK 8192
#define MDIM  1024
#define EEXP  8
#define HDIM  4096
#define HHALF 2048
#define CAP   1024

typedef __attribute__((ext_vector_type(8))) short short8v;   // 8 bf16 in 4 VGPRs
typedef __attribute__((ext_vector_type(4))) float f32x4;

__device__ __forceinline__ short f2bf(float f) {
    __bf16 b = (__bf16)f;                 // RNE hardware convert on gfx950
    return __builtin_bit_cast(short, b);
}

__device__ __forceinline__ void gld_lds16(const void* g, void* l) {
    __builtin_amdgcn_global_load_lds(
        (const __attribute__((address_space(1))) void*)g,
        (__attribute__((address_space(3))) void*)l, 16, 0, 0);
}

#define BAR() asm volatile("s_barrier" ::: "memory")
#define WAIT_VM(N) asm volatile("s_waitcnt vmcnt(" #N ")" ::: "memory")

// ---------------------------------------------------------------------------
// K1: gating. One wave per token, fp64 accumulation -> exactly-rounded logits
// so argmax matches the numpy reference. graw = 1/sum(exp(l-m)).
// Also zeroes the token's output row and clears slot_token (folded memsets).
// ---------------------------------------------------------------------------
__global__ void gate_kernel(const float* __restrict__ x, const float* __restrict__ wg,
                            int* __restrict__ eidx, float* __restrict__ graw,
                            float* __restrict__ out, int* __restrict__ slot_token) {
    const int wave = threadIdx.x >> 6, lane = threadIdx.x & 63;
    const int tok = blockIdx.x * 4 + wave;

    float* orow = out + (size_t)tok * MDIM;
    const float4 z = {0.f, 0.f, 0.f, 0.f};
#pragma unroll
    for (int i2 = 0; i2 < 4; ++i2)
        *(float4*)(orow + i2 * 256 + lane * 4) = z;
    if (lane == 0) slot_token[tok] = -1;

    const float* xr = x + (size_t)tok * MDIM;
    double acc[8] = {0, 0, 0, 0, 0, 0, 0, 0};
#pragma unroll
    for (int kk = 0; kk < 16; ++kk) {
        int i = kk * 64 + lane;
        float xv = xr[i];
        float4 w0 = *(const float4*)(wg + (size_t)i * 8);
        float4 w1v = *(const float4*)(wg + (size_t)i * 8 + 4);
        acc[0] += (double)xv * (double)w0.x;
        acc[1] += (double)xv * (double)w0.y;
        acc[2] += (double)xv * (double)w0.z;
        acc[3] += (double)xv * (double)w0.w;
        acc[4] += (double)xv * (double)w1v.x;
        acc[5] += (double)xv * (double)w1v.y;
        acc[6] += (double)xv * (double)w1v.z;
        acc[7] += (double)xv * (double)w1v.w;
    }
#pragma unroll
    for (int off = 32; off >= 1; off >>= 1) {
#pragma unroll
        for (int e = 0; e < 8; ++e) acc[e] += __shfl_down(acc[e], off);
    }
    if (lane == 0) {
        float l[8];
#pragma unroll
        for (int e = 0; e < 8; ++e) l[e] = (float)acc[e];
        float m = l[0]; int best = 0;
#pragma unroll
        for (int e = 1; e < 8; ++e) { if (l[e] > m) { m = l[e]; best = e; } }
        float den = 0.f;
#pragma unroll
        for (int e = 0; e < 8; ++e) den += expf(l[e] - m);
        eidx[tok] = best;
        graw[tok] = 1.0f / den;
    }
}

// ---------------------------------------------------------------------------
// K2: capacity scan. One block; pos[t] = count of earlier same-expert tokens.
// ---------------------------------------------------------------------------
__global__ void scan_kernel(const int* __restrict__ eidx, const float* __restrict__ graw,
                            float* __restrict__ gfin, int* __restrict__ slot_token) {
    __shared__ int cnt[256][8];
    __shared__ int pfx[256][8];
    const int t = threadIdx.x;
    const int base = t * 32;
    int local[8] = {0, 0, 0, 0, 0, 0, 0, 0};
    for (int j = 0; j < 32; ++j) {
        int ev = eidx[base + j];
#pragma unroll
        for (int e = 0; e < 8; ++e) local[e] += (ev == e);
    }
#pragma unroll
    for (int e = 0; e < 8; ++e) cnt[t][e] = local[e];
    __syncthreads();
    if (t < 8) {
        int run = 0;
        for (int i = 0; i < 256; ++i) { pfx[i][t] = run; run += cnt[i][t]; }
    }
    __syncthreads();
    int run[8];
#pragma unroll
    for (int e = 0; e < 8; ++e) run[e] = pfx[t][e];
    for (int j = 0; j < 32; ++j) {
        int tok = base + j;
        int ev = eidx[tok];
        int pos = 0;
#pragma unroll
        for (int e = 0; e < 8; ++e) { if (ev == e) pos = run[e]; run[e] += (ev == e); }
        if (pos < CAP) {
            gfin[tok] = graw[tok];
            slot_token[ev * CAP + pos] = tok;
        } else {
            gfin[tok] = 0.f;
        }
    }
}

// ---------------------------------------------------------------------------
// K3: dispatch — gather kept token rows into bf16 dispA[E*CAP][MDIM].
// ---------------------------------------------------------------------------
__global__ void dispatch_kernel(const float* __restrict__ x, const int* __restrict__ slot_token,
                                short* __restrict__ dispA) {
    const int slot = blockIdx.x;
    const int tok = slot_token[slot];
    const int t = threadIdx.x;
    short4 ov;
    if (tok >= 0) {
        float4 v = *(const float4*)(x + (size_t)tok * MDIM + t * 4);
        ov.x = f2bf(v.x); ov.y = f2bf(v.y); ov.z = f2bf(v.z); ov.w = f2bf(v.w);
    } else {
        ov.x = 0; ov.y = 0; ov.z = 0; ov.w = 0;
    }
    *(short4*)(dispA + (size_t)slot * MDIM + t * 4) = ov;
}

// ---------------------------------------------------------------------------
// K4: fp32 -> bf16 cast + transpose of an [R][C] slab into [C][R] bf16.
// ---------------------------------------------------------------------------
__global__ void cast_transpose_kernel(const float* __restrict__ in, short* __restrict__ out,
                                      int R, int C, int rstride,
                                      size_t in_estride, size_t out_estride) {
    __shared__ float tile[64][65];
    const int e = blockIdx.z;
    const float* src = in + (size_t)e * in_estride;
    short* dst = out + (size_t)e * out_estride;
    const int r0 = blockIdx.x * 64, c0 = blockIdx.y * 64;
    const int t = threadIdx.x;
    const int rr = t >> 4, cq = (t & 15) * 4;
#pragma unroll
    for (int j = 0; j < 4; ++j) {
        int r = rr + j * 16;
        float4 v = *(const float4*)(src + (size_t)(r0 + r) * rstride + c0 + cq);
        tile[r][cq + 0] = v.x; tile[r][cq + 1] = v.y;
        tile[r][cq + 2] = v.z; tile[r][cq + 3] = v.w;
    }
    __syncthreads();
    const int oc = t >> 2, ch = (t & 3) * 16;
    union { short s[16]; int4 v2[2]; } u;
#pragma unroll
    for (int j = 0; j < 16; ++j) u.s[j] = f2bf(tile[ch + j][oc]);
    int4* dp = (int4*)(dst + (size_t)(c0 + oc) * R + r0 + ch);
    dp[0] = u.v2[0]; dp[1] = u.v2[1];
}

// ---------------------------------------------------------------------------
// GEMM core R7: BK=32 K-panels, 3-slot ring, distance-2 prefetch, counted
// vmcnt, ONE s_barrier per K-step.
//
// LDS per operand: [3 slot][ROWS][32] bf16, 64B rows. A = 48 KB;
// B = 48 KB (BN=256) or 24 KB (BN=128). Frag read = ds_read_b128 at
// row*64B + fq*16B: 64 lanes hit each bank exactly 8x (the b128 floor) ->
// conflict-free with LINEAR layout, no swizzle, linear global_load_lds.
//
// Step t: [issue stage(t+2) -> slot (t+2)%3] [ds_read frags(t) from slot
// t%3] [MFMA] [WAIT_VM(L) — leaves t+2's L loads in flight, confirms t+1,
// which has had ~2 steps of flight] [s_barrier]. Slot (t+2)%3's previous
// reads finished before step t-1's end barrier -> no clobber race. Tail
// (t+2>=NT): WAIT_VM(0) (confirms the final tile; nothing newer in flight).
//
// Fragment maps (HW-verified m89/m91):
//   A: A[m=lane&15][k=(lane>>4)*8+j];  B: Bt[n=lane&15][k=(lane>>4)*8+j]
//   C/D: col=lane&15, row=(lane>>4)*4+reg
// ---------------------------------------------------------------------------
template <int ROWS>
__device__ __forceinline__ void stage_panel(const short* __restrict__ g, int K,
                                            int k0, short* lds) {
    // ROWS x 32 bf16 panel, 64B rows: each gld_lds16 covers 16 rows
    // (64 lanes x 16B = 1 KB). Lane l -> row l>>2, chunk l&3. Linear dest.
    const int t = threadIdx.x, w = t >> 6, l = t & 63;
    const int r = l >> 2, c = (l & 3) * 8;
#pragma unroll
    for (int j = 0; j < ROWS / 128; ++j) {
        const int rg = j * 128 + w * 16;
        gld_lds16(g + (size_t)(rg + r) * K + k0 + c, lds + rg * 32);
    }
}

__device__ __forceinline__ short8v rdpanel(const short* panel, int row, int fq) {
    return *(const short8v*)(panel + row * 32 + fq * 8);
}

template <int BN, int K, int NWC>
__device__ __forceinline__ void gemm_core(const short* __restrict__ A,
                                          const short* __restrict__ B,
                                          int m0, int n0,
                                          short* __restrict__ ldsA,
                                          short* __restrict__ ldsB,
                                          f32x4 (&acc)[2 * NWC][BN / NWC / 16]) {
    constexpr int NT = K / 32;
    constexpr int MF = 2 * NWC;          // A frags / wave / step
    constexpr int NF = BN / NWC / 16;    // B frags / wave / step
    const int tid = threadIdx.x;
    const int wid = tid >> 6, lane = tid & 63;
    const int wr = wid / NWC, wcn = wid % NWC;
    const int fr = lane & 15, fq = lane >> 4;
    const int rowA0 = wr * (MF * 16);
    const int rowB0 = wcn * (NF * 16);

    const short* Ab = A + (size_t)m0 * K;
    const short* Bb = B + (size_t)n0 * K;

    // prologue: panels t=0 (slot 0) and t=1 (slot 1); confirm t=0 only.
    stage_panel<256>(Ab, K, 0, ldsA);
    stage_panel<BN >(Bb, K, 0, ldsB);
    stage_panel<256>(Ab, K, 32, ldsA + 256 * 32);
    stage_panel<BN >(Bb, K, 32, ldsB + BN * 32);
    if constexpr (BN == 256) { WAIT_VM(4); } else { WAIT_VM(3); }
    BAR();

    int s0 = 0, s2 = 2;
#pragma unroll 1
    for (int t = 0; t < NT; ++t) {
        if (t + 2 < NT) {
            stage_panel<256>(Ab, K, (t + 2) * 32, ldsA + s2 * (256 * 32));
            stage_panel<BN >(Bb, K, (t + 2) * 32, ldsB + s2 * (BN * 32));
        }
        const short* pA = ldsA + s0 * (256 * 32);
        const short* pB = ldsB + s0 * (BN * 32);
        short8v av[MF], bv[NF];
#pragma unroll
        for (int i = 0; i < MF; ++i)
            av[i] = rdpanel(pA, rowA0 + i * 16 + fr, fq);
#pragma unroll
        for (int j = 0; j < NF; ++j)
            bv[j] = rdpanel(pB, rowB0 + j * 16 + fr, fq);
        __builtin_amdgcn_s_setprio(1);
#pragma unroll
        for (int i = 0; i < MF; ++i)
#pragma unroll
            for (int j = 0; j < NF; ++j)
                acc[i][j] = __builtin_amdgcn_mfma_f32_16x16x32_bf16(
                    av[i], bv[j], acc[i][j], 0, 0, 0);
        __builtin_amdgcn_s_setprio(0);
        if (t + 2 < NT) {
            if constexpr (BN == 256) { WAIT_VM(4); } else { WAIT_VM(3); }
        } else {
            WAIT_VM(0);
        }
        BAR();
        s0 = (s0 == 2) ? 0 : s0 + 1;
        s2 = (s2 == 2) ? 0 : s2 + 1;
    }
}

// Bijective expert->XCD remap: grid is (4,8,8)=256 blocks; blocks with
// lin%8==k (one XCD) become one expert's 32 tiles -> that expert's weight
// panel lives in that XCD's private L2.
__device__ __forceinline__ int3 remap_block() {
    int lin = blockIdx.x + (blockIdx.y << 2) + (blockIdx.z << 5);
    lin = (lin & 7) * 32 + (lin >> 3);
    int3 r;
    r.z = lin >> 5;          // expert
    r.x = lin & 3;           // m-tile
    r.y = (lin >> 2) & 7;    // n-tile
    return r;
}

// GEMM1 half: h[e,c,n] = relu(dispA[e,c,:].w1t[e,n,:] + b1[e,hoff+n])
// Tile 256x256, waves 2Mx4N (per-wave 128x64, acc[8][4]).
__global__ __launch_bounds__(512, 2)
void gemm1_kernel(const short* __restrict__ dispA, const short* __restrict__ w1t,
                  const float* __restrict__ b1, short* __restrict__ h, int hoff) {
    __shared__ alignas(16) short ldsA[3 * 256 * 32];
    __shared__ alignas(16) short ldsB[3 * 256 * 32];
    const int3 bid = remap_block();
    const int e = bid.z;
    const int m0 = bid.x * 256, n0 = bid.y * 256;

    f32x4 acc[8][4];
#pragma unroll
    for (int i = 0; i < 8; ++i)
#pragma unroll
        for (int j = 0; j < 4; ++j) acc[i][j] = (f32x4){0.f, 0.f, 0.f, 0.f};

    gemm_core<256, MDIM, 4>(dispA + (size_t)e * CAP * MDIM,
                            w1t + (size_t)e * HHALF * MDIM, m0, n0, ldsA, ldsB, acc);

    const int wid = threadIdx.x >> 6, lane = threadIdx.x & 63;
    const int wr = wid >> 2, wcn = wid & 3, fr = lane & 15, fq = lane >> 4;
    const float* b1e = b1 + (size_t)e * HDIM + hoff;
    short* hExp = h + (size_t)e * CAP * HHALF;
#pragma unroll
    for (int nf = 0; nf < 4; ++nf) {
        const int gcol = n0 + wcn * 64 + nf * 16 + fr;
        const float bias = b1e[gcol];
#pragma unroll
        for (int mf = 0; mf < 8; ++mf)
#pragma unroll
            for (int r2 = 0; r2 < 4; ++r2) {
                const int grow = m0 + wr * 128 + mf * 16 + fq * 4 + r2;
                float v = acc[mf][nf][r2] + bias;
                hExp[(size_t)grow * HHALF + gcol] = f2bf(v > 0.f ? v : 0.f);
            }
    }
}

// GEMM2 half: eo_part[e,c,m] = h[e,c,:].w2t[e,m,:]; scatter (acc[+b2])*gv.
// Tile 256x128, waves 4Mx2N (per-wave 64x64, acc[4][4]).
__global__ __launch_bounds__(512, 2)
void gemm2_kernel(const short* __restrict__ h, const short* __restrict__ w2t,
                  const float* __restrict__ b2, const int* __restrict__ slot_token,
                  const float* __restrict__ gfin, float* __restrict__ out,
                  int acc_flag) {
    __shared__ alignas(16) short ldsA[3 * 256 * 32];
    __shared__ alignas(16) short ldsB[3 * 128 * 32];
    const int3 bid = remap_block();
    const int e = bid.z;
    const int m0 = bid.x * 256, n0 = bid.y * 128;

    f32x4 acc[4][4];
#pragma unroll
    for (int i = 0; i < 4; ++i)
#pragma unroll
        for (int j = 0; j < 4; ++j) acc[i][j] = (f32x4){0.f, 0.f, 0.f, 0.f};

    gemm_core<128, HHALF, 2>(h + (size_t)e * CAP * HHALF,
                             w2t + (size_t)e * MDIM * HHALF, m0, n0, ldsA, ldsB, acc);

    const int wid = threadIdx.x >> 6, lane = threadIdx.x & 63;
    const int wr = wid >> 1, wcn = wid & 1, fr = lane & 15, fq = lane >> 4;
    const float* b2e = b2 + (size_t)e * MDIM;
#pragma unroll
    for (int mf = 0; mf < 4; ++mf)
#pragma unroll
        for (int r2 = 0; r2 < 4; ++r2) {
            const int grow = m0 + wr * 64 + mf * 16 + fq * 4 + r2;
            const int tok = slot_token[e * CAP + grow];
            if (tok < 0) continue;
            const float gv = gfin[tok];
            float* orow = out + (size_t)tok * MDIM;
            if (acc_flag == 0) {
#pragma unroll
                for (int nf = 0; nf < 4; ++nf) {
                    const int gcol = n0 + wcn * 64 + nf * 16 + fr;
                    orow[gcol] = (acc[mf][nf][r2] + b2e[gcol]) * gv;
                }
            } else {
#pragma unroll
                for (int nf = 0; nf < 4; ++nf) {
                    const int gcol = n0 + wcn * 64 + nf * 16 + fr;
                    orow[gcol] += acc[mf][nf][r2] * gv;
                }
            }
        }
}

// ---------------------------------------------------------------------------
// Workspace layout (bytes) — TOTAL 84,017,152 B (~80.1 MiB):
//   wt    bf16 [E][2048][1024] ping-pong :        0 .. 33,554,432
//   hbuf  bf16 [E][C][HHALF]             : 33,554,432 .. 67,108,864
//   dispA bf16 [E*C][M]                  : 67,108,864 .. 83,886,080
//   eidx/graw/gfin/slot_token            : 83,886,080 .. 84,017,152
// ---------------------------------------------------------------------------
extern "C" void kernel_launch(void* const* d_in, const int* in_sizes, int n_in,
                              void* d_out, int out_size, void* d_ws, size_t ws_size,
                              hipStream_t stream) {
    const float* x  = (const float*)d_in[0];
    const float* wg = (const float*)d_in[1];
    const float* w1 = (const float*)d_in[2];
    const float* b1 = (const float*)d_in[3];
    const float* w2 = (const float*)d_in[4];
    const float* b2 = (const float*)d_in[5];
    float* out = (float*)d_out;

    char* ws = (char*)d_ws;
    short* wt    = (short*)(ws);
    short* hbuf  = (short*)(ws + 33554432);
    short* dispA = (short*)(ws + 67108864);
    int*   eidx  = (int*)  (ws + 83886080);
    float* graw  = (float*)(ws + 83886080 + 32768);
    float* gfin  = (float*)(ws + 83886080 + 65536);
    int*   slot_token = (int*)(ws + 83886080 + 98304);

    // memsets folded into gate_kernel (out-row zero + slot_token clear)
    gate_kernel<<<S_TOK / 4, 256, 0, stream>>>(x, wg, eidx, graw, out, slot_token);
    scan_kernel<<<1, 256, 0, stream>>>(eidx, graw, gfin, slot_token);
    dispatch_kernel<<<EEXP * CAP, 256, 0, stream>>>(x, slot_token, dispA);

    for (int half = 0; half < 2; ++half) {
        // w1 slab: in [E][M][H], rows r=M (stride H), cols c = hoff..hoff+2048
        cast_transpose_kernel<<<dim3(MDIM / 64, HHALF / 64, EEXP), 256, 0, stream>>>(
            w1 + (size_t)half * HHALF, wt, MDIM, HHALF, HDIM,
            (size_t)MDIM * HDIM, (size_t)HHALF * MDIM);
        gemm1_kernel<<<dim3(4, 8, 8), 512, 0, stream>>>(
            dispA, wt, b1, hbuf, half * HHALF);
        // w2 slab: in [E][H][M], rows r = hoff..hoff+2048 (stride M), cols c=M
        cast_transpose_kernel<<<dim3(HHALF / 64, MDIM / 64, EEXP), 256, 0, stream>>>(
            w2 + (size_t)half * HHALF * MDIM, wt, HHALF, MDIM, MDIM,
            (size_t)HDIM * MDIM, (size_t)MDIM * HHALF);
        gemm2_kernel<<<dim3(4, 8, 8), 512, 0, stream>>>(
            hbuf, wt, b2, slot_token, gfin, out, half);
    }
}